// Round 11
// baseline (342.363 us; speedup 1.0000x reference)
//
#include <hip/hip_runtime.h>
#include <hip/hip_bf16.h>
#include <stdint.h>

#define BATCH 32
#define NPART 10
#define BP_TOT 320
#define DM 256
#define FF 1024
#define OD 32
#define SL 512
#define NCHUNK 4
#define CROWS 128   // rows per chunk

#define SQRT_SIGMA 0.31622776601683794f

// native vector type accepted by __builtin_nontemporal_store
typedef float nfloat4 __attribute__((ext_vector_type(4)));

__device__ __forceinline__ void nt_store4(const float4& v, float* p) {
    nfloat4 nv;
    nv.x = v.x; nv.y = v.y; nv.z = v.z; nv.w = v.w;
    __builtin_nontemporal_store(nv, (nfloat4*)p);
}

// ---------------- threefry2x32 (JAX-exact, key = (0, 42)) ----------------
__device__ __forceinline__ uint32_t rotl32(uint32_t x, uint32_t r) {
    return (x << r) | (x >> (32u - r));
}

__device__ __forceinline__ void threefry2x32(uint32_t k0, uint32_t k1,
                                             uint32_t x0, uint32_t x1,
                                             uint32_t& o0, uint32_t& o1) {
    uint32_t k2 = k0 ^ k1 ^ 0x1BD11BDAu;
    uint32_t x = x0 + k0, y = x1 + k1;
#define TFR(r) { x += y; y = rotl32(y, r); y ^= x; }
    TFR(13u) TFR(15u) TFR(26u) TFR(6u)
    x += k1; y += k2 + 1u;
    TFR(17u) TFR(29u) TFR(16u) TFR(24u)
    x += k2; y += k0 + 2u;
    TFR(13u) TFR(15u) TFR(26u) TFR(6u)
    x += k0; y += k1 + 3u;
    TFR(17u) TFR(29u) TFR(16u) TFR(24u)
    x += k1; y += k2 + 4u;
    TFR(13u) TFR(15u) TFR(26u) TFR(6u)
    x += k2; y += k0 + 5u;
#undef TFR
    o0 = x; o1 = y;
}

__device__ __forceinline__ float jax_gumbel_part(uint32_t m) {
    const float TINY = 1.17549435e-38f;
    uint32_t o0, o1;
    threefry2x32(0u, 42u, 0u, m, o0, o1);
    uint32_t bits = o0 ^ o1;
    uint32_t fb = (bits >> 9) | 0x3f800000u;
    float f = __uint_as_float(fb) - 1.0f;
    float u = fmaxf(TINY, f + TINY);
    return -logf(-logf(u));
}

// ---------------- K2: qkv(folded) + flash-decode chunk + identity copy-out ----
// grid (320, 4) x 256. Every chunk computes q redundantly; the chunk owning
// row t also computes k,v and writes knew/vnew.
__global__ __launch_bounds__(256) void attn_chunk_kernel(
    const float* __restrict__ Kin, const float* __restrict__ Vin,
    const float* __restrict__ x,
    const float* __restrict__ nq, const float* __restrict__ nk,
    const float* __restrict__ nv,
    const float* __restrict__ wq_w, const float* __restrict__ wq_b,
    const float* __restrict__ wk_w, const float* __restrict__ wk_b,
    const float* __restrict__ wv_w, const float* __restrict__ wv_b,
    const int* __restrict__ t_ptr,
    float* __restrict__ knew, float* __restrict__ vnew,
    float* __restrict__ Kout, float* __restrict__ Vout,
    float* __restrict__ logits, float* __restrict__ zpart,
    float* __restrict__ mstat)
{
    const int bp   = blockIdx.x;
    const int sc   = blockIdx.y;        // 0..3
    const int tid  = threadIdx.x;
    const int lane = tid & 63;
    const int wave = tid >> 6;          // 0..3
    const int t    = *t_ptr;

    __shared__ float xs[DM], qs[DM], ks[DM], vs[DM];
    __shared__ float att_loc[CROWS];
    __shared__ float scratch[4 * 256];
    __shared__ float redm[2], rede[2];

    xs[tid] = x[bp * DM + tid];
    __syncthreads();

    // q projection (all chunks, redundant but L2-hot)
    {
        float a0 = 0.f, a1 = 0.f, a2 = 0.f, a3 = 0.f;
        #pragma unroll 4
        for (int i = 0; i < 64; ++i) {
            a0 = fmaf(xs[i],       wq_w[(i      ) * DM + tid], a0);
            a1 = fmaf(xs[i +  64], wq_w[(i +  64) * DM + tid], a1);
            a2 = fmaf(xs[i + 128], wq_w[(i + 128) * DM + tid], a2);
            a3 = fmaf(xs[i + 192], wq_w[(i + 192) * DM + tid], a3);
        }
        qs[tid] = (a0 + a1) + (a2 + a3) + wq_b[tid]
                + SQRT_SIGMA * nq[bp * DM + tid];
    }

    const int s0c = sc * CROWS;
    const bool has_t = (t >= s0c) && (t < s0c + CROWS);
    if (has_t) {
        float k0 = 0.f, k1 = 0.f, k2 = 0.f, k3 = 0.f;
        float v0 = 0.f, v1 = 0.f, v2 = 0.f, v3 = 0.f;
        #pragma unroll 2
        for (int i = 0; i < 64; ++i) {
            float x0 = xs[i], x1 = xs[i + 64], x2 = xs[i + 128], x3 = xs[i + 192];
            k0 = fmaf(x0, wk_w[(i      ) * DM + tid], k0);
            k1 = fmaf(x1, wk_w[(i +  64) * DM + tid], k1);
            k2 = fmaf(x2, wk_w[(i + 128) * DM + tid], k2);
            k3 = fmaf(x3, wk_w[(i + 192) * DM + tid], k3);
            v0 = fmaf(x0, wv_w[(i      ) * DM + tid], v0);
            v1 = fmaf(x1, wv_w[(i +  64) * DM + tid], v1);
            v2 = fmaf(x2, wv_w[(i + 128) * DM + tid], v2);
            v3 = fmaf(x3, wv_w[(i + 192) * DM + tid], v3);
        }
        float kv = (k0 + k1) + (k2 + k3) + wk_b[tid] + SQRT_SIGMA * nk[bp * DM + tid];
        float vv = (v0 + v1) + (v2 + v3) + wv_b[tid] + SQRT_SIGMA * nv[bp * DM + tid];
        ks[tid] = kv; vs[tid] = vv;
        knew[(size_t)bp * DM + tid] = kv;
        vnew[(size_t)bp * DM + tid] = vv;
    }
    __syncthreads();

    const float* Kbp = Kin + (size_t)bp * SL * DM;
    const float* Vbp = Vin + (size_t)bp * SL * DM;
    float4 q4 = *(const float4*)&qs[lane * 4];
    const int s0 = s0c + wave * 32;

    // phase A: logits + identity copy-out of K rows s>t (NT)
    for (int j0 = 0; j0 < 32; j0 += 8) {
        float4 k4[8];
        #pragma unroll
        for (int u = 0; u < 8; ++u) {
            int s = s0 + j0 + u;
            k4[u] = (s == t) ? *(const float4*)&ks[lane * 4]
                             : *(const float4*)&Kbp[(size_t)s * DM + lane * 4];
        }
        #pragma unroll
        for (int u = 0; u < 8; ++u) {
            int s = s0 + j0 + u;
            if (s > t)
                nt_store4(k4[u], Kout + ((size_t)bp * SL + s) * DM + lane * 4);
            float acc = q4.x * k4[u].x + q4.y * k4[u].y + q4.z * k4[u].z + q4.w * k4[u].w;
            #pragma unroll
            for (int off = 32; off; off >>= 1) acc += __shfl_down(acc, off);
            if (lane == 0) {
                float l = acc * 0.0625f;
                att_loc[wave * 32 + j0 + u] = l;
                logits[(size_t)bp * SL + s] = l;
            }
        }
    }
    __syncthreads();

    // phase B: local max / exp / sum over 128 chunk logits (waves 0,1)
    float l = (tid < CROWS) ? att_loc[tid] : -3.402823466e+38f;
    float mm = l;
    #pragma unroll
    for (int off = 32; off; off >>= 1) mm = fmaxf(mm, __shfl_down(mm, off));
    if (tid < CROWS && lane == 0) redm[wave] = mm;
    __syncthreads();
    const float m_loc = fmaxf(redm[0], redm[1]);
    float p = (tid < CROWS) ? expf(l - m_loc) : 0.f;
    if (tid < CROWS) att_loc[tid] = p;
    float e = p;
    #pragma unroll
    for (int off = 32; off; off >>= 1) e += __shfl_down(e, off);
    if (tid < CROWS && lane == 0) rede[wave] = e;
    __syncthreads();
    const float e_loc = rede[0] + rede[1];

    // phase C: z-partial + identity copy-out of V rows s>t (NT)
    float4 z4 = make_float4(0.f, 0.f, 0.f, 0.f);
    for (int j0 = 0; j0 < 32; j0 += 8) {
        float4 v4[8];
        #pragma unroll
        for (int u = 0; u < 8; ++u) {
            int s = s0 + j0 + u;
            v4[u] = (s == t) ? *(const float4*)&vs[lane * 4]
                             : *(const float4*)&Vbp[(size_t)s * DM + lane * 4];
        }
        #pragma unroll
        for (int u = 0; u < 8; ++u) {
            int s = s0 + j0 + u;
            if (s > t)
                nt_store4(v4[u], Vout + ((size_t)bp * SL + s) * DM + lane * 4);
            float a = att_loc[wave * 32 + j0 + u];
            z4.x = fmaf(a, v4[u].x, z4.x);
            z4.y = fmaf(a, v4[u].y, z4.y);
            z4.z = fmaf(a, v4[u].z, z4.z);
            z4.w = fmaf(a, v4[u].w, z4.w);
        }
    }
    *(float4*)&scratch[wave * 256 + lane * 4] = z4;
    __syncthreads();
    if (tid < DM) {
        float zp = (scratch[tid] + scratch[256 + tid]) + (scratch[512 + tid] + scratch[768 + tid]);
        zpart[((size_t)bp * NCHUNK + sc) * DM + tid] = zp;
    }
    if (tid == 0) {
        mstat[((size_t)bp * NCHUNK + sc) * 2 + 0] = m_loc;
        mstat[((size_t)bp * NCHUNK + sc) * 2 + 1] = e_loc;
    }
}

// ---------------- K3: combine + zproj + LN1 + FFN + LN2, 2 particles/block ----
// grid 160 x 1024. Weight matrices read once per block, feed both particles.
__global__ __launch_bounds__(1024) void post_kernel(
    const float* __restrict__ x, const float* __restrict__ nz,
    const float* __restrict__ logits, const float* __restrict__ zpart,
    const float* __restrict__ mstat,
    const float* __restrict__ wz_w, const float* __restrict__ wz_b,
    const float* __restrict__ ln1_g, const float* __restrict__ ln1_b,
    const float* __restrict__ w1, const float* __restrict__ b1,
    const float* __restrict__ w2, const float* __restrict__ b2,
    const float* __restrict__ ln2_g, const float* __restrict__ ln2_b,
    float* __restrict__ attn_out, float* __restrict__ r_out)
{
    const int bb   = blockIdx.x;     // 0..159
    const int tid  = threadIdx.x;    // 0..1023
    const int lane = tid & 63;
    const int bp0  = bb * 2;

    __shared__ float bufz[2][DM];    // z, then ln1-out
    __shared__ float xs2[2][DM];
    __shared__ float hid[2][FF];
    __shared__ float part[4][2][DM]; // [i-chunk][g][d]
    __shared__ float red[2][8];

    // ---- phase 0a: combine stats for both particles ----
    float gmv[2], invv[2], fcs[2][NCHUNK];
    #pragma unroll
    for (int g = 0; g < 2; ++g) {
        const float* ms = mstat + (size_t)(bp0 + g) * (2 * NCHUNK);
        float mc[NCHUNK], ec[NCHUNK];
        float gm = -3.402823466e+38f;
        #pragma unroll
        for (int c = 0; c < NCHUNK; ++c) {
            mc[c] = ms[2 * c]; ec[c] = ms[2 * c + 1];
            gm = fmaxf(gm, mc[c]);
        }
        float denom = 0.f;
        #pragma unroll
        for (int c = 0; c < NCHUNK; ++c) {
            fcs[g][c] = expf(mc[c] - gm);
            denom = fmaf(ec[c], fcs[g][c], denom);
        }
        gmv[g] = gm; invv[g] = 1.0f / denom;
    }

    // ---- phase 0b: attention weights (all threads, one each) ----
    {
        int ga = tid >> 9, s = tid & 511;
        float l = logits[(size_t)(bp0 + ga) * SL + s];
        __builtin_nontemporal_store(expf(l - gmv[ga]) * invv[ga],
                                    attn_out + (size_t)(bp0 + ga) * SL + s);
    }
    // ---- phase 0c: z combine + x load ----
    if (tid < 512) {
        int g = tid >> 8, d = tid & 255;
        const float* zp = zpart + (size_t)(bp0 + g) * NCHUNK * DM;
        float z = 0.f;
        #pragma unroll
        for (int c = 0; c < NCHUNK; ++c) z = fmaf(zp[c * DM + d], fcs[g][c], z);
        bufz[g][d] = z * invv[g];
    } else {
        int r2 = tid - 512;
        int g = r2 >> 8, d = r2 & 255;
        xs2[g][d] = x[(size_t)(bp0 + g) * DM + d];
    }
    __syncthreads();

    // ---- phase 1: z projection; thread = (i-chunk, d), 2 accs ----
    {
        int ic = tid >> 8, d = tid & 255;
        const int i0 = ic * 64;
        float p0 = 0.f, p1 = 0.f;
        #pragma unroll 4
        for (int ii = 0; ii < 64; ++ii) {
            float wv = wz_w[(i0 + ii) * DM + d];
            p0 = fmaf(bufz[0][i0 + ii], wv, p0);
            p1 = fmaf(bufz[1][i0 + ii], wv, p1);
        }
        part[ic][0][d] = p0; part[ic][1][d] = p1;
    }
    __syncthreads();

    const int gg = (tid >> 8) & 1;   // particle for LN threads (tid<512)
    const int dd = tid & 255;
    const int wv4 = (tid >> 6) & 3;  // wave within particle group
    float h = 0.f, o = 0.f;
    if (tid < 512) {
        float az = (part[0][gg][dd] + part[1][gg][dd]) + (part[2][gg][dd] + part[3][gg][dd]);
        h = az + wz_b[dd] + SQRT_SIGMA * nz[(size_t)(bp0 + gg) * DM + dd] + xs2[gg][dd];
    }

    // ---- phase 2: layernorm 1 (waves 0-3: g0, waves 4-7: g1) ----
    float s1 = h;
    #pragma unroll
    for (int off = 32; off; off >>= 1) s1 += __shfl_down(s1, off);
    if (tid < 512 && lane == 0) red[gg][wv4] = s1;
    __syncthreads();
    if (tid < 512) {
        float mu = (red[gg][0] + red[gg][1] + red[gg][2] + red[gg][3]) * (1.0f / DM);
        h -= mu;
    }
    float s2 = h * h;
    #pragma unroll
    for (int off = 32; off; off >>= 1) s2 += __shfl_down(s2, off);
    if (tid < 512 && lane == 0) red[gg][4 + wv4] = s2;
    __syncthreads();
    if (tid < 512) {
        float var = (red[gg][4] + red[gg][5] + red[gg][6] + red[gg][7]) * (1.0f / DM);
        o = h * rsqrtf(var + 1e-6f) * ln1_g[dd] + ln1_b[dd];
        bufz[gg][dd] = o;
    }
    __syncthreads();

    // ---- phase 3: FFN1; thread owns hid j=tid for BOTH particles ----
    {
        float c0 = 0.f, c1 = 0.f;
        #pragma unroll 4
        for (int i = 0; i < DM; ++i) {
            float wv = w1[i * FF + tid];
            c0 = fmaf(bufz[0][i], wv, c0);
            c1 = fmaf(bufz[1][i], wv, c1);
        }
        float bb1 = b1[tid];
        hid[0][tid] = fmaxf(c0 + bb1, 0.f);
        hid[1][tid] = fmaxf(c1 + bb1, 0.f);
    }
    __syncthreads();

    // ---- phase 4: FFN2; thread = (i-chunk, d), 2 accs ----
    {
        int ic = tid >> 8, d = tid & 255;
        const int i0 = ic * 256;
        float p0 = 0.f, p1 = 0.f;
        #pragma unroll 4
        for (int ii = 0; ii < 256; ++ii) {
            float wv = w2[(i0 + ii) * DM + d];
            p0 = fmaf(hid[0][i0 + ii], wv, p0);
            p1 = fmaf(hid[1][i0 + ii], wv, p1);
        }
        part[ic][0][d] = p0; part[ic][1][d] = p1;
    }
    __syncthreads();
    float rr = 0.f;
    if (tid < 512) {
        rr = (part[0][gg][dd] + part[1][gg][dd]) + (part[2][gg][dd] + part[3][gg][dd])
           + b2[dd] + o;
    }

    // ---- phase 5: layernorm 2 ----
    float t1 = rr;
    #pragma unroll
    for (int off = 32; off; off >>= 1) t1 += __shfl_down(t1, off);
    if (tid < 512 && lane == 0) red[gg][wv4] = t1;
    __syncthreads();
    if (tid < 512) {
        float mu2 = (red[gg][0] + red[gg][1] + red[gg][2] + red[gg][3]) * (1.0f / DM);
        rr -= mu2;
    }
    float t2 = rr * rr;
    #pragma unroll
    for (int off = 32; off; off >>= 1) t2 += __shfl_down(t2, off);
    if (tid < 512 && lane == 0) red[gg][4 + wv4] = t2;
    __syncthreads();
    if (tid < 512) {
        float var2 = (red[gg][4] + red[gg][5] + red[gg][6] + red[gg][7]) * (1.0f / DM);
        float rf = rr * rsqrtf(var2 + 1e-6f) * ln2_g[dd] + ln2_b[dd];
        r_out[(size_t)(bp0 + gg) * DM + dd] = rf;
    }
}

// ---------------- K4: particle weights + resample indices ----------------
__global__ __launch_bounds__(320) void weights_kernel(
    const float* __restrict__ r, const float* __restrict__ y,
    const float* __restrict__ out_w, const float* __restrict__ out_b,
    float* __restrict__ w_out, int* __restrict__ i_t)
{
    const int b   = blockIdx.x;    // 0..31
    const int tid = threadIdx.x;   // 0..319
    const int p   = tid >> 5;      // 0..9
    const int j   = tid & 31;      // 0..31

    __shared__ float sred[NPART];
    __shared__ float es[NPART];
    __shared__ float pe[NPART];
    __shared__ float wsm[NPART];

    const float* rrow = r + (size_t)(b * NPART + p) * DM;
    float acc = 0.f;
    #pragma unroll 4
    for (int i = 0; i < DM; ++i) acc = fmaf(rrow[i], out_w[i * OD + j], acc);
    float pred = acc + out_b[j];
    float muv  = y[(size_t)(b * NPART + p) * OD + j] - pred;
    float s    = muv * muv;
    #pragma unroll
    for (int off = 16; off; off >>= 1) s += __shfl_down(s, off, 32);
    if (j == 0) sred[p] = s;   // log_w = -s
    __syncthreads();

    if (tid < NPART) es[tid] = expf(-sred[tid]);
    __syncthreads();
    if (tid < NPART) {
        float mx = es[0];
        #pragma unroll
        for (int i = 1; i < NPART; ++i) mx = fmaxf(mx, es[i]);
        pe[tid] = expf(es[tid] - mx);
    }
    __syncthreads();
    if (tid < NPART) {
        float sum = 0.f;
        #pragma unroll
        for (int i = 0; i < NPART; ++i) sum += pe[i];
        float wv = pe[tid] / sum;
        w_out[b * NPART + tid] = wv;
        wsm[tid] = wv;
    }
    __syncthreads();

    if (tid < NPART) {
        int pp = tid;
        int best = 0;
        float bests = -3.402823466e+38f;
        #pragma unroll
        for (int jj = 0; jj < NPART; ++jj) {
            uint32_t m = (uint32_t)(b * 100 + pp * 10 + jj);
            float score = jax_gumbel_part(m) + wsm[jj];
            if (score > bests) { bests = score; best = jj; }
        }
        i_t[b * NPART + pp] = best;
    }
}

// ---------------- K5: resample gather-copy, 8 rows/block, NT stores ----------
// y=0: V rows s<=t, y=1: K rows s<=t, y=2: R all rows.
__global__ __launch_bounds__(256) void resample_kernel(
    const float* __restrict__ Kin, const float* __restrict__ Vin,
    const float* __restrict__ Rin,
    const float* __restrict__ knew, const float* __restrict__ vnew,
    const float* __restrict__ rnew,
    const int* __restrict__ i_t, const int* __restrict__ t_ptr,
    float* __restrict__ Kout, float* __restrict__ Vout, float* __restrict__ Rout)
{
    const int t    = *t_ptr;
    const int ysel = blockIdx.y;            // 0=V 1=K 2=R
    const int tid  = threadIdx.x;

    const float* gat = (ysel == 1) ? Kin : (ysel == 0) ? Vin : Rin;
    const float* nb  = (ysel == 1) ? knew : (ysel == 0) ? vnew : rnew;
    float* outb      = (ysel == 1) ? Kout : (ysel == 0) ? Vout : Rout;

    #pragma unroll
    for (int half = 0; half < 2; ++half) {
        size_t f4i = (size_t)blockIdx.x * 512 + half * 256 + tid;
        int lane4 = (int)(f4i & 63);
        int row   = (int)(f4i >> 6);        // 0..163839
        int bpi   = row >> 9;
        int s     = row & 511;

        if (ysel != 2 && s > t) continue;   // K/V identity rows done in K2

        int b     = bpi / NPART;
        int p     = bpi - b * NPART;
        int srcp  = (s <= t) ? i_t[bpi] : p;
        int src_bpi = b * NPART + srcp;

        const float* src = (s == t) ? nb + (size_t)src_bpi * DM
                                    : gat + ((size_t)src_bpi * SL + s) * DM;
        float4 v4 = *(const float4*)(src + (size_t)lane4 * 4);
        nt_store4(v4, outb + (size_t)row * DM + (size_t)lane4 * 4);
    }
}

// ---------------- launch ----------------
extern "C" void kernel_launch(void* const* d_in, const int* in_sizes, int n_in,
                              void* d_out, int out_size, void* d_ws, size_t ws_size,
                              hipStream_t stream) {
    const float* x    = (const float*)d_in[0];
    const float* y    = (const float*)d_in[1];
    const float* Kin  = (const float*)d_in[2];
    const float* Vin  = (const float*)d_in[3];
    const float* Rin  = (const float*)d_in[4];
    const float* nq   = (const float*)d_in[5];
    const float* nk   = (const float*)d_in[6];
    const float* nv   = (const float*)d_in[7];
    const float* nz   = (const float*)d_in[8];
    const int*   tptr = (const int*)d_in[9];
    const float* wq_w = (const float*)d_in[10];
    const float* wq_b = (const float*)d_in[11];
    const float* wk_w = (const float*)d_in[12];
    const float* wk_b = (const float*)d_in[13];
    const float* wv_w = (const float*)d_in[14];
    const float* wv_b = (const float*)d_in[15];
    const float* wz_w = (const float*)d_in[16];
    const float* wz_b = (const float*)d_in[17];
    const float* ln1g = (const float*)d_in[18];
    const float* ln1b = (const float*)d_in[19];
    const float* w1   = (const float*)d_in[20];
    const float* b1   = (const float*)d_in[21];
    const float* w2   = (const float*)d_in[22];
    const float* b2   = (const float*)d_in[23];
    const float* ln2g = (const float*)d_in[24];
    const float* ln2b = (const float*)d_in[25];
    const float* outw = (const float*)d_in[26];
    const float* outb = (const float*)d_in[27];

    float* out = (float*)d_out;
    const size_t R_ELEMS    = (size_t)BP_TOT * DM;        // 81920
    const size_t ATTN_ELEMS = (size_t)BP_TOT * SL;        // 163840
    const size_t KVR_ELEMS  = (size_t)BP_TOT * SL * DM;   // 41943040
    float* r_out    = out;
    float* attn_out = out + R_ELEMS;
    float* K_out    = out + R_ELEMS + ATTN_ELEMS;
    float* V_out    = K_out + KVR_ELEMS;
    float* R_out    = V_out + KVR_ELEMS;
    float* w_out    = R_out + KVR_ELEMS;

    float* knew = (float*)d_ws;
    float* vnew = knew + R_ELEMS;
    int*   i_t  = (int*)(vnew + R_ELEMS);

    // scratch in the R_out head (dead until K5 overwrites it):
    float* logits = R_out;                                    // 320*512
    float* zpart  = R_out + ATTN_ELEMS;                       // 320*4*256
    float* mstat  = zpart + (size_t)BP_TOT * NCHUNK * DM;     // 320*8

    // K2: qkv + flash-decode chunks + identity copy-out of K/V rows s>t
    attn_chunk_kernel<<<dim3(BP_TOT, NCHUNK), 256, 0, stream>>>(
        Kin, Vin, x, nq, nk, nv,
        wq_w, wq_b, wk_w, wk_b, wv_w, wv_b, tptr,
        knew, vnew, K_out, V_out, logits, zpart, mstat);

    // K3: combine + attn_out + zproj + LN1 + FFN + LN2 (2 particles/block)
    post_kernel<<<BP_TOT / 2, 1024, 0, stream>>>(
        x, nz, logits, zpart, mstat,
        wz_w, wz_b, ln1g, ln1b, w1, b1, w2, b2, ln2g, ln2b,
        attn_out, r_out);

    weights_kernel<<<BATCH, 320, 0, stream>>>(
        r_out, y, outw, outb, w_out, i_t);

    // K5: 8 rows/block, 2 float4/thread
    resample_kernel<<<dim3(163840 / 8, 3), 256, 0, stream>>>(
        Kin, Vin, Rin, knew, vnew, r_out, i_t, tptr,
        K_out, V_out, R_out);
}

// Round 12
// 308.768 us; speedup vs baseline: 1.1088x; 1.1088x over previous
//
#include <hip/hip_runtime.h>
#include <hip/hip_bf16.h>
#include <stdint.h>

#define BATCH 32
#define NPART 10
#define BP_TOT 320
#define DM 256
#define FF 1024
#define OD 32
#define SL 512
#define NCHUNK 4
#define CROWS 128   // rows per chunk

#define SQRT_SIGMA 0.31622776601683794f

// native vector type accepted by nontemporal builtins
typedef float nfloat4 __attribute__((ext_vector_type(4)));

__device__ __forceinline__ void nt_store4(const float4& v, float* p) {
    nfloat4 nv;
    nv.x = v.x; nv.y = v.y; nv.z = v.z; nv.w = v.w;
    __builtin_nontemporal_store(nv, (nfloat4*)p);
}

__device__ __forceinline__ float4 nt_load4(const float* p) {
    nfloat4 nv = __builtin_nontemporal_load((const nfloat4*)p);
    return make_float4(nv.x, nv.y, nv.z, nv.w);
}

// ---------------- threefry2x32 (JAX-exact, key = (0, 42)) ----------------
__device__ __forceinline__ uint32_t rotl32(uint32_t x, uint32_t r) {
    return (x << r) | (x >> (32u - r));
}

__device__ __forceinline__ void threefry2x32(uint32_t k0, uint32_t k1,
                                             uint32_t x0, uint32_t x1,
                                             uint32_t& o0, uint32_t& o1) {
    uint32_t k2 = k0 ^ k1 ^ 0x1BD11BDAu;
    uint32_t x = x0 + k0, y = x1 + k1;
#define TFR(r) { x += y; y = rotl32(y, r); y ^= x; }
    TFR(13u) TFR(15u) TFR(26u) TFR(6u)
    x += k1; y += k2 + 1u;
    TFR(17u) TFR(29u) TFR(16u) TFR(24u)
    x += k2; y += k0 + 2u;
    TFR(13u) TFR(15u) TFR(26u) TFR(6u)
    x += k0; y += k1 + 3u;
    TFR(17u) TFR(29u) TFR(16u) TFR(24u)
    x += k1; y += k2 + 4u;
    TFR(13u) TFR(15u) TFR(26u) TFR(6u)
    x += k2; y += k0 + 5u;
#undef TFR
    o0 = x; o1 = y;
}

__device__ __forceinline__ float jax_gumbel_part(uint32_t m) {
    const float TINY = 1.17549435e-38f;
    uint32_t o0, o1;
    threefry2x32(0u, 42u, 0u, m, o0, o1);
    uint32_t bits = o0 ^ o1;
    uint32_t fb = (bits >> 9) | 0x3f800000u;
    float f = __uint_as_float(fb) - 1.0f;
    float u = fmaxf(TINY, f + TINY);
    return -logf(-logf(u));
}

// ---------------- K1: QKV projections, 4 particles/block, grid (80, 3) ----------
__global__ __launch_bounds__(256) void qkv_kernel(
    const float* __restrict__ x,
    const float* __restrict__ nq, const float* __restrict__ nk,
    const float* __restrict__ nv,
    const float* __restrict__ wq_w, const float* __restrict__ wq_b,
    const float* __restrict__ wk_w, const float* __restrict__ wk_b,
    const float* __restrict__ wv_w, const float* __restrict__ wv_b,
    float* __restrict__ qtmp, float* __restrict__ knew, float* __restrict__ vnew)
{
    const int bb = blockIdx.x;      // 0..79
    const int m  = blockIdx.y;      // 0..2
    const int d  = threadIdx.x;     // 0..255

    __shared__ float xs[4][DM];
    #pragma unroll
    for (int g = 0; g < 4; ++g) xs[g][d] = x[(bb * 4 + g) * DM + d];
    __syncthreads();

    const float* W; const float* bias; const float* noise;
    if (m == 0)      { W = wq_w; bias = wq_b; noise = nq; }
    else if (m == 1) { W = wk_w; bias = wk_b; noise = nk; }
    else             { W = wv_w; bias = wv_b; noise = nv; }

    float a0 = 0.f, a1 = 0.f, a2 = 0.f, a3 = 0.f;
    #pragma unroll 4
    for (int i = 0; i < DM; ++i) {
        float wv = W[i * DM + d];
        a0 = fmaf(xs[0][i], wv, a0);
        a1 = fmaf(xs[1][i], wv, a1);
        a2 = fmaf(xs[2][i], wv, a2);
        a3 = fmaf(xs[3][i], wv, a3);
    }
    float r[4] = {a0, a1, a2, a3};
    #pragma unroll
    for (int g = 0; g < 4; ++g) {
        int bp = bb * 4 + g;
        float v = r[g] + bias[d] + SQRT_SIGMA * noise[bp * DM + d];
        if (m == 0)      qtmp[(size_t)bp * SL + d] = v;
        else if (m == 1) knew[(size_t)bp * DM + d] = v;
        else             vnew[(size_t)bp * DM + d] = v;
    }
}

// ---------------- K2: flash-decode chunk (128 rows) + identity copy-out --------
// grid (320, 4) x 256. NT stores for identity copy-out.
__global__ __launch_bounds__(256) void attn_chunk_kernel(
    const float* __restrict__ Kin, const float* __restrict__ Vin,
    const float* __restrict__ knew, const float* __restrict__ vnew,
    const float* __restrict__ qtmp, const int* __restrict__ t_ptr,
    float* __restrict__ Kout, float* __restrict__ Vout,
    float* __restrict__ logits, float* __restrict__ zpart,
    float* __restrict__ mstat)
{
    const int bp   = blockIdx.x;
    const int sc   = blockIdx.y;        // 0..3
    const int tid  = threadIdx.x;
    const int lane = tid & 63;
    const int wave = tid >> 6;          // 0..3
    const int t    = *t_ptr;

    __shared__ float qs[DM], ks[DM], vs[DM];
    __shared__ float att_loc[CROWS];
    __shared__ float scratch[4 * 256];
    __shared__ float redm[2], rede[2];

    if (tid < DM) {
        qs[tid] = qtmp[(size_t)bp * SL + tid];
        ks[tid] = knew[(size_t)bp * DM + tid];
        vs[tid] = vnew[(size_t)bp * DM + tid];
    }
    __syncthreads();

    const float* Kbp = Kin + (size_t)bp * SL * DM;
    const float* Vbp = Vin + (size_t)bp * SL * DM;
    float4 q4 = *(const float4*)&qs[lane * 4];
    const int s0 = sc * CROWS + wave * 32;

    // phase A: logits + identity copy-out of K rows s>t (NT)
    for (int j0 = 0; j0 < 32; j0 += 8) {
        float4 k4[8];
        #pragma unroll
        for (int u = 0; u < 8; ++u) {
            int s = s0 + j0 + u;
            k4[u] = (s == t) ? *(const float4*)&ks[lane * 4]
                             : *(const float4*)&Kbp[(size_t)s * DM + lane * 4];
        }
        #pragma unroll
        for (int u = 0; u < 8; ++u) {
            int s = s0 + j0 + u;
            if (s > t)
                nt_store4(k4[u], Kout + ((size_t)bp * SL + s) * DM + lane * 4);
            float acc = q4.x * k4[u].x + q4.y * k4[u].y + q4.z * k4[u].z + q4.w * k4[u].w;
            #pragma unroll
            for (int off = 32; off; off >>= 1) acc += __shfl_down(acc, off);
            if (lane == 0) {
                float l = acc * 0.0625f;
                att_loc[wave * 32 + j0 + u] = l;
                logits[(size_t)bp * SL + s] = l;
            }
        }
    }
    __syncthreads();

    // phase B: local max / exp / sum over 128 chunk logits (waves 0,1)
    float l = (tid < CROWS) ? att_loc[tid] : -3.402823466e+38f;
    float mm = l;
    #pragma unroll
    for (int off = 32; off; off >>= 1) mm = fmaxf(mm, __shfl_down(mm, off));
    if (tid < CROWS && lane == 0) redm[wave] = mm;
    __syncthreads();
    const float m_loc = fmaxf(redm[0], redm[1]);
    float p = (tid < CROWS) ? expf(l - m_loc) : 0.f;
    if (tid < CROWS) att_loc[tid] = p;
    float e = p;
    #pragma unroll
    for (int off = 32; off; off >>= 1) e += __shfl_down(e, off);
    if (tid < CROWS && lane == 0) rede[wave] = e;
    __syncthreads();
    const float e_loc = rede[0] + rede[1];

    // phase C: z-partial + identity copy-out of V rows s>t (NT)
    float4 z4 = make_float4(0.f, 0.f, 0.f, 0.f);
    for (int j0 = 0; j0 < 32; j0 += 8) {
        float4 v4[8];
        #pragma unroll
        for (int u = 0; u < 8; ++u) {
            int s = s0 + j0 + u;
            v4[u] = (s == t) ? *(const float4*)&vs[lane * 4]
                             : *(const float4*)&Vbp[(size_t)s * DM + lane * 4];
        }
        #pragma unroll
        for (int u = 0; u < 8; ++u) {
            int s = s0 + j0 + u;
            if (s > t)
                nt_store4(v4[u], Vout + ((size_t)bp * SL + s) * DM + lane * 4);
            float a = att_loc[wave * 32 + j0 + u];
            z4.x = fmaf(a, v4[u].x, z4.x);
            z4.y = fmaf(a, v4[u].y, z4.y);
            z4.z = fmaf(a, v4[u].z, z4.z);
            z4.w = fmaf(a, v4[u].w, z4.w);
        }
    }
    *(float4*)&scratch[wave * 256 + lane * 4] = z4;
    __syncthreads();
    if (tid < DM) {
        float zp = (scratch[tid] + scratch[256 + tid]) + (scratch[512 + tid] + scratch[768 + tid]);
        zpart[((size_t)bp * NCHUNK + sc) * DM + tid] = zp;
    }
    if (tid == 0) {
        mstat[((size_t)bp * NCHUNK + sc) * 2 + 0] = m_loc;
        mstat[((size_t)bp * NCHUNK + sc) * 2 + 1] = e_loc;
    }
}

// ---------------- K3: combine + zproj + LN1 + FFN + LN2, per particle --------
// grid 320 x 1024.
__global__ __launch_bounds__(1024) void post_kernel(
    const float* __restrict__ x, const float* __restrict__ nz,
    const float* __restrict__ logits, const float* __restrict__ zpart,
    const float* __restrict__ mstat,
    const float* __restrict__ wz_w, const float* __restrict__ wz_b,
    const float* __restrict__ ln1_g, const float* __restrict__ ln1_b,
    const float* __restrict__ w1, const float* __restrict__ b1,
    const float* __restrict__ w2, const float* __restrict__ b2,
    const float* __restrict__ ln2_g, const float* __restrict__ ln2_b,
    float* __restrict__ attn_out, float* __restrict__ r_out)
{
    const int bp   = blockIdx.x;
    const int tid  = threadIdx.x;
    const int lane = tid & 63;
    const int wave = tid >> 6;
    const int grp  = tid >> 8;      // 0..3
    const int qtid = tid & 255;

    __shared__ float buf[DM];       // z, then ln1-out
    __shared__ float xs[DM];
    __shared__ float hid[FF];
    __shared__ float scratch[1024];
    __shared__ float red[32];

    // ---- phase 0: combine chunk stats; all threads derive gm/inv ----
    const float* ms = mstat + (size_t)bp * (2 * NCHUNK);
    float mc[NCHUNK], ec[NCHUNK];
    float gm = -3.402823466e+38f;
    #pragma unroll
    for (int c = 0; c < NCHUNK; ++c) {
        mc[c] = ms[2 * c]; ec[c] = ms[2 * c + 1];
        gm = fmaxf(gm, mc[c]);
    }
    float fc[NCHUNK], denom = 0.f;
    #pragma unroll
    for (int c = 0; c < NCHUNK; ++c) {
        fc[c] = expf(mc[c] - gm);
        denom = fmaf(ec[c], fc[c], denom);
    }
    const float inv = 1.0f / denom;

    if (tid < 512) {
        float l = logits[(size_t)bp * SL + tid];
        __builtin_nontemporal_store(expf(l - gm) * inv,
                                    attn_out + (size_t)bp * SL + tid);
    } else if (tid < 768) {
        int d = tid - 512;
        const float* zp = zpart + (size_t)bp * NCHUNK * DM;
        float z = 0.f;
        #pragma unroll
        for (int c = 0; c < NCHUNK; ++c) z = fmaf(zp[c * DM + d], fc[c], z);
        buf[d] = z * inv;
    } else {
        int d = tid - 768;
        xs[d] = x[bp * DM + d];
    }
    __syncthreads();

    // ---- phase 1: z projection, i-split 4 ways ----
    {
        const int i0 = grp * 64;
        float a0 = 0.f, a1 = 0.f;
        #pragma unroll 4
        for (int ii = 0; ii < 32; ++ii) {
            a0 = fmaf(buf[i0 + ii],      wz_w[(i0 + ii)      * DM + qtid], a0);
            a1 = fmaf(buf[i0 + ii + 32], wz_w[(i0 + ii + 32) * DM + qtid], a1);
        }
        scratch[grp * 256 + qtid] = a0 + a1;
    }
    __syncthreads();
    float h = 0.f;
    if (tid < DM) {
        float az = (scratch[tid] + scratch[256 + tid]) + (scratch[512 + tid] + scratch[768 + tid]);
        h = az + wz_b[tid] + SQRT_SIGMA * nz[bp * DM + tid] + xs[tid];
    }

    // ---- phase 2: layernorm 1 ----
    float s1 = h;
    #pragma unroll
    for (int off = 32; off; off >>= 1) s1 += __shfl_down(s1, off);
    if (lane == 0) red[wave] = s1;
    __syncthreads();
    float mu = (red[0] + red[1] + red[2] + red[3]) * (1.0f / DM);
    float dv = (tid < DM) ? (h - mu) : 0.f;
    float s2 = dv * dv;
    #pragma unroll
    for (int off = 32; off; off >>= 1) s2 += __shfl_down(s2, off);
    if (lane == 0) red[16 + wave] = s2;
    __syncthreads();
    float var = (red[16] + red[17] + red[18] + red[19]) * (1.0f / DM);
    float o = 0.f;
    __syncthreads();
    if (tid < DM) {
        o = dv * rsqrtf(var + 1e-6f) * ln1_g[tid] + ln1_b[tid];
        buf[tid] = o;
    }
    __syncthreads();

    // ---- phase 3: FFN1 (256 -> 1024) ----
    {
        float h0 = 0.f, h1 = 0.f, h2 = 0.f, h3 = 0.f;
        #pragma unroll 4
        for (int i = 0; i < 64; ++i) {
            h0 = fmaf(buf[i],       w1[(i      ) * FF + tid], h0);
            h1 = fmaf(buf[i +  64], w1[(i +  64) * FF + tid], h1);
            h2 = fmaf(buf[i + 128], w1[(i + 128) * FF + tid], h2);
            h3 = fmaf(buf[i + 192], w1[(i + 192) * FF + tid], h3);
        }
        hid[tid] = fmaxf((h0 + h1) + (h2 + h3) + b1[tid], 0.f);
    }
    __syncthreads();

    // ---- phase 4: FFN2 (1024 -> 256), i-split 4 ways ----
    {
        const int i0 = grp * 256;
        float a0 = 0.f, a1 = 0.f, a2 = 0.f, a3 = 0.f;
        #pragma unroll 4
        for (int ii = 0; ii < 64; ++ii) {
            a0 = fmaf(hid[i0 + ii],       w2[(i0 + ii      ) * DM + qtid], a0);
            a1 = fmaf(hid[i0 + ii +  64], w2[(i0 + ii +  64) * DM + qtid], a1);
            a2 = fmaf(hid[i0 + ii + 128], w2[(i0 + ii + 128) * DM + qtid], a2);
            a3 = fmaf(hid[i0 + ii + 192], w2[(i0 + ii + 192) * DM + qtid], a3);
        }
        scratch[grp * 256 + qtid] = (a0 + a1) + (a2 + a3);
    }
    __syncthreads();
    float rr = 0.f;
    if (tid < DM) {
        rr = (scratch[tid] + scratch[256 + tid]) + (scratch[512 + tid] + scratch[768 + tid])
           + b2[tid] + o;
    }

    // ---- phase 5: layernorm 2 ----
    float t1 = rr;
    #pragma unroll
    for (int off = 32; off; off >>= 1) t1 += __shfl_down(t1, off);
    if (lane == 0) red[wave] = t1;
    __syncthreads();
    float mu2 = (red[0] + red[1] + red[2] + red[3]) * (1.0f / DM);
    float dv2 = (tid < DM) ? (rr - mu2) : 0.f;
    float t2 = dv2 * dv2;
    #pragma unroll
    for (int off = 32; off; off >>= 1) t2 += __shfl_down(t2, off);
    if (lane == 0) red[16 + wave] = t2;
    __syncthreads();
    float var2 = (red[16] + red[17] + red[18] + red[19]) * (1.0f / DM);
    if (tid < DM) {
        float rf = dv2 * rsqrtf(var2 + 1e-6f) * ln2_g[tid] + ln2_b[tid];
        r_out[(size_t)bp * DM + tid] = rf;
    }
}

// ---------------- K4: particle weights + resample indices ----------------
__global__ __launch_bounds__(320) void weights_kernel(
    const float* __restrict__ r, const float* __restrict__ y,
    const float* __restrict__ out_w, const float* __restrict__ out_b,
    float* __restrict__ w_out, int* __restrict__ i_t)
{
    const int b   = blockIdx.x;    // 0..31
    const int tid = threadIdx.x;   // 0..319
    const int p   = tid >> 5;      // 0..9
    const int j   = tid & 31;      // 0..31

    __shared__ float sred[NPART];
    __shared__ float es[NPART];
    __shared__ float pe[NPART];
    __shared__ float wsm[NPART];

    const float* rrow = r + (size_t)(b * NPART + p) * DM;
    float acc = 0.f;
    #pragma unroll 4
    for (int i = 0; i < DM; ++i) acc = fmaf(rrow[i], out_w[i * OD + j], acc);
    float pred = acc + out_b[j];
    float muv  = y[(size_t)(b * NPART + p) * OD + j] - pred;
    float s    = muv * muv;
    #pragma unroll
    for (int off = 16; off; off >>= 1) s += __shfl_down(s, off, 32);
    if (j == 0) sred[p] = s;   // log_w = -s
    __syncthreads();

    if (tid < NPART) es[tid] = expf(-sred[tid]);
    __syncthreads();
    if (tid < NPART) {
        float mx = es[0];
        #pragma unroll
        for (int i = 1; i < NPART; ++i) mx = fmaxf(mx, es[i]);
        pe[tid] = expf(es[tid] - mx);
    }
    __syncthreads();
    if (tid < NPART) {
        float sum = 0.f;
        #pragma unroll
        for (int i = 0; i < NPART; ++i) sum += pe[i];
        float wv = pe[tid] / sum;
        w_out[b * NPART + tid] = wv;
        wsm[tid] = wv;
    }
    __syncthreads();

    if (tid < NPART) {
        int pp = tid;
        int best = 0;
        float bests = -3.402823466e+38f;
        #pragma unroll
        for (int jj = 0; jj < NPART; ++jj) {
            uint32_t m = (uint32_t)(b * 100 + pp * 10 + jj);
            float score = jax_gumbel_part(m) + wsm[jj];
            if (score > bests) { bests = score; best = jj; }
        }
        i_t[b * NPART + pp] = best;
    }
}

// ---------------- K5: resample gather-copy, 8 rows/block, NT loads+stores ----
// y=0: V rows s<=t, y=1: K rows s<=t, y=2: R all rows.
__global__ __launch_bounds__(256) void resample_kernel(
    const float* __restrict__ Kin, const float* __restrict__ Vin,
    const float* __restrict__ Rin,
    const float* __restrict__ knew, const float* __restrict__ vnew,
    const float* __restrict__ rnew,
    const int* __restrict__ i_t, const int* __restrict__ t_ptr,
    float* __restrict__ Kout, float* __restrict__ Vout, float* __restrict__ Rout)
{
    const int t    = *t_ptr;
    const int ysel = blockIdx.y;            // 0=V 1=K 2=R
    const int tid  = threadIdx.x;

    const float* gat = (ysel == 1) ? Kin : (ysel == 0) ? Vin : Rin;
    const float* nb  = (ysel == 1) ? knew : (ysel == 0) ? vnew : rnew;
    float* outb      = (ysel == 1) ? Kout : (ysel == 0) ? Vout : Rout;

    #pragma unroll
    for (int half = 0; half < 2; ++half) {
        size_t f4i = (size_t)blockIdx.x * 512 + half * 256 + tid;
        int lane4 = (int)(f4i & 63);
        int row   = (int)(f4i >> 6);        // 0..163839
        int bpi   = row >> 9;
        int s     = row & 511;

        if (ysel != 2 && s > t) continue;   // K/V identity rows done in K2

        int b     = bpi / NPART;
        int p     = bpi - b * NPART;
        int srcp  = (s <= t) ? i_t[bpi] : p;
        int src_bpi = b * NPART + srcp;

        const float* src = (s == t) ? nb + (size_t)src_bpi * DM
                                    : gat + ((size_t)src_bpi * SL + s) * DM;
        float4 v4 = nt_load4(src + (size_t)lane4 * 4);
        nt_store4(v4, outb + (size_t)row * DM + (size_t)lane4 * 4);
    }
}

// ---------------- launch ----------------
extern "C" void kernel_launch(void* const* d_in, const int* in_sizes, int n_in,
                              void* d_out, int out_size, void* d_ws, size_t ws_size,
                              hipStream_t stream) {
    const float* x    = (const float*)d_in[0];
    const float* y    = (const float*)d_in[1];
    const float* Kin  = (const float*)d_in[2];
    const float* Vin  = (const float*)d_in[3];
    const float* Rin  = (const float*)d_in[4];
    const float* nq   = (const float*)d_in[5];
    const float* nk   = (const float*)d_in[6];
    const float* nv   = (const float*)d_in[7];
    const float* nz   = (const float*)d_in[8];
    const int*   tptr = (const int*)d_in[9];
    const float* wq_w = (const float*)d_in[10];
    const float* wq_b = (const float*)d_in[11];
    const float* wk_w = (const float*)d_in[12];
    const float* wk_b = (const float*)d_in[13];
    const float* wv_w = (const float*)d_in[14];
    const float* wv_b = (const float*)d_in[15];
    const float* wz_w = (const float*)d_in[16];
    const float* wz_b = (const float*)d_in[17];
    const float* ln1g = (const float*)d_in[18];
    const float* ln1b = (const float*)d_in[19];
    const float* w1   = (const float*)d_in[20];
    const float* b1   = (const float*)d_in[21];
    const float* w2   = (const float*)d_in[22];
    const float* b2   = (const float*)d_in[23];
    const float* ln2g = (const float*)d_in[24];
    const float* ln2b = (const float*)d_in[25];
    const float* outw = (const float*)d_in[26];
    const float* outb = (const float*)d_in[27];

    float* out = (float*)d_out;
    const size_t R_ELEMS    = (size_t)BP_TOT * DM;        // 81920
    const size_t ATTN_ELEMS = (size_t)BP_TOT * SL;        // 163840
    const size_t KVR_ELEMS  = (size_t)BP_TOT * SL * DM;   // 41943040
    float* r_out    = out;
    float* attn_out = out + R_ELEMS;
    float* K_out    = out + R_ELEMS + ATTN_ELEMS;
    float* V_out    = K_out + KVR_ELEMS;
    float* R_out    = V_out + KVR_ELEMS;
    float* w_out    = R_out + KVR_ELEMS;

    float* knew = (float*)d_ws;
    float* vnew = knew + R_ELEMS;
    int*   i_t  = (int*)(vnew + R_ELEMS);

    // scratch in the R_out head (dead until K5 overwrites it):
    float* logits = R_out;                                    // 320*512
    float* zpart  = R_out + ATTN_ELEMS;                       // 320*4*256
    float* mstat  = zpart + (size_t)BP_TOT * NCHUNK * DM;     // 320*8

    // K1: q -> attn_out scratch, k/v -> ws (4 particles/block)
    qkv_kernel<<<dim3(BP_TOT / 4, 3), 256, 0, stream>>>(
        x, nq, nk, nv, wq_w, wq_b, wk_w, wk_b, wv_w, wv_b,
        attn_out, knew, vnew);

    // K2: flash-decode chunks + identity copy-out of K/V rows s>t
    attn_chunk_kernel<<<dim3(BP_TOT, NCHUNK), 256, 0, stream>>>(
        Kin, Vin, knew, vnew, attn_out, tptr,
        K_out, V_out, logits, zpart, mstat);

    // K3: combine + attn_out + zproj + LN1 + FFN + LN2 (per particle)
    post_kernel<<<BP_TOT, 1024, 0, stream>>>(
        x, nz, logits, zpart, mstat,
        wz_w, wz_b, ln1g, ln1b, w1, b1, w2, b2, ln2g, ln2b,
        attn_out, r_out);

    weights_kernel<<<BATCH, 320, 0, stream>>>(
        r_out, y, outw, outb, w_out, i_t);

    // K5: 8 rows/block, 2 float4/thread
    resample_kernel<<<dim3(163840 / 8, 3), 256, 0, stream>>>(
        Kin, Vin, Rin, knew, vnew, r_out, i_t, tptr,
        K_out, V_out, R_out);
}